// Round 1
// baseline (2364.236 us; speedup 1.0000x reference)
//
#include <hip/hip_runtime.h>
#include <hip/hip_fp16.h>

#define T_SEQ 4096
#define NBATCH 4
#define EDIM 1024
#define ADIM 1024
#define MTOT (NBATCH * T_SEQ)  // 16384

typedef _Float16 f16x8 __attribute__((ext_vector_type(8)));
typedef float f32x4 __attribute__((ext_vector_type(4)));

// ---------------- Kernel 1: cast + transpose weights to f16 ----------------
// Wt[z][n][k] = W_z[k][n], z in {0:Wk, 1:Wq, 2:Wv}
__global__ __launch_bounds__(256) void cast_transpose_w(
    const float* __restrict__ Wk, const float* __restrict__ Wq,
    const float* __restrict__ Wv, _Float16* __restrict__ Wt) {
  __shared__ float tile[32][33];
  const int z = blockIdx.z;
  const float* W = (z == 0) ? Wk : (z == 1) ? Wq : Wv;
  const int n0 = blockIdx.x * 32, k0 = blockIdx.y * 32;
  const int tx = threadIdx.x, ty = threadIdx.y;  // block (32,8)
#pragma unroll
  for (int yy = 0; yy < 32; yy += 8)
    tile[ty + yy][tx] = W[(size_t)(k0 + ty + yy) * ADIM + n0 + tx];
  __syncthreads();
  _Float16* out = Wt + (size_t)z * EDIM * ADIM;
#pragma unroll
  for (int yy = 0; yy < 32; yy += 8)
    out[(size_t)(n0 + ty + yy) * EDIM + k0 + tx] = (_Float16)tile[tx][ty + yy];
}

// ---------------- Kernel 2: QKV projection GEMM ----------------
// C[m][n] = sum_k X[m][k] * Wt[n][k];  z=0 -> K, z=1 -> Q, z=2 -> V (transposed out)
__global__ __launch_bounds__(256) void gemm_qkv(
    const float* __restrict__ X, const _Float16* __restrict__ Wt,
    _Float16* __restrict__ Qb, _Float16* __restrict__ Kb,
    _Float16* __restrict__ Vt) {
  const int z = blockIdx.z;
  const _Float16* Bt = Wt + (size_t)z * EDIM * ADIM;
  __shared__ __align__(16) _Float16 Al[128 * 32];
  __shared__ __align__(16) _Float16 Bl[128 * 32];
  const int tid = threadIdx.x;
  const int lane = tid & 63, w = tid >> 6;
  const int wm = w >> 1, wn = w & 1;
  const int lr = lane & 15, g = lane >> 4;
  const int m0 = blockIdx.y * 128, n0 = blockIdx.x * 128;
  const int arow = tid >> 1;      // 0..127
  const int ahalf = tid & 1;      // which 16-elem half of the 32-wide row

  f32x4 acc[4][4] = {};

  for (int k0 = 0; k0 < EDIM; k0 += 32) {
    // --- stage A (f32 -> f16, reg-staged) ---
    {
      const float* src = X + (size_t)(m0 + arow) * EDIM + k0 + ahalf * 16;
      float4 v0 = ((const float4*)src)[0];
      float4 v1 = ((const float4*)src)[1];
      float4 v2 = ((const float4*)src)[2];
      float4 v3 = ((const float4*)src)[3];
      f16x8 pa = {(_Float16)v0.x, (_Float16)v0.y, (_Float16)v0.z, (_Float16)v0.w,
                  (_Float16)v1.x, (_Float16)v1.y, (_Float16)v1.z, (_Float16)v1.w};
      f16x8 pb = {(_Float16)v2.x, (_Float16)v2.y, (_Float16)v2.z, (_Float16)v2.w,
                  (_Float16)v3.x, (_Float16)v3.y, (_Float16)v3.z, (_Float16)v3.w};
      *(f16x8*)&Al[arow * 32 + ahalf * 16] = pa;
      *(f16x8*)&Al[arow * 32 + ahalf * 16 + 8] = pb;
    }
    // --- stage B via global_load_lds (16B/lane, wave-uniform LDS base) ---
#pragma unroll
    for (int t = 0; t < 2; ++t) {
      const int r0 = (w * 2 + t) * 16;
      const _Float16* gsrc =
          Bt + (size_t)(n0 + r0 + (lane >> 2)) * EDIM + k0 + (lane & 3) * 8;
      __builtin_amdgcn_global_load_lds(
          (const __attribute__((address_space(1))) void*)gsrc,
          (__attribute__((address_space(3))) void*)&Bl[r0 * 32], 16, 0, 0);
    }
    __syncthreads();
    // --- fragments + MFMA ---
    f16x8 af[4], bf[4];
#pragma unroll
    for (int i = 0; i < 4; i++)
      af[i] = *(const f16x8*)&Al[(wm * 64 + i * 16 + lr) * 32 + g * 8];
#pragma unroll
    for (int j = 0; j < 4; j++)
      bf[j] = *(const f16x8*)&Bl[(wn * 64 + j * 16 + lr) * 32 + g * 8];
#pragma unroll
    for (int i = 0; i < 4; i++)
#pragma unroll
      for (int j = 0; j < 4; j++)
        acc[i][j] = __builtin_amdgcn_mfma_f32_16x16x32_f16(af[i], bf[j], acc[i][j], 0, 0, 0);
    __syncthreads();
  }

  // --- epilogue ---
#pragma unroll
  for (int i = 0; i < 4; i++)
#pragma unroll
    for (int j = 0; j < 4; j++)
#pragma unroll
      for (int r = 0; r < 4; r++) {
        const int row = m0 + wm * 64 + i * 16 + 4 * g + r;
        const int col = n0 + wn * 64 + j * 16 + lr;
        const _Float16 hv = (_Float16)acc[i][j][r];
        if (z == 0)
          Kb[(size_t)row * ADIM + col] = hv;
        else if (z == 1)
          Qb[(size_t)row * ADIM + col] = hv;
        else {
          const int b = row >> 12, tt = row & 4095;
          Vt[((size_t)b * ADIM + col) * T_SEQ + tt] = hv;
        }
      }
}

// ---------------- Kernel 3: causal flash attention ----------------
// 512 threads = 8 waves: wq = w>>2 (16-query half), wf = w&3 (256-feature quarter)
__global__ __launch_bounds__(512) void flash_attn(
    const _Float16* __restrict__ Qb, const _Float16* __restrict__ Kb,
    const _Float16* __restrict__ Vt, float* __restrict__ Out) {
  __shared__ float S_lds[8 * 512];  // [w][16 rows][32 cols] partials
  __shared__ float S_red[2 * 512];  // [wq][16][32] reduced
  const int tid = threadIdx.x;
  const int lane = tid & 63, w = tid >> 6;
  const int wq = w >> 2, wf = w & 3;
  const int lr = lane & 15, g = lane >> 4;
  const int b = blockIdx.y;
  const int qb = gridDim.x - 1 - blockIdx.x;  // heavy blocks dispatch first
  const int q0 = qb * 32;
  const int fbase = wf * 256;
  const int qrow = q0 + wq * 16 + lr;  // query row this lane tracks for softmax

  // Q fragments: 16 queries x 256 features, k = ks*32 + 8g + j
  f16x8 qf[8];
  const _Float16* Qrow =
      Qb + (size_t)(b * T_SEQ + q0 + wq * 16 + lr) * ADIM + fbase + g * 8;
#pragma unroll
  for (int ks = 0; ks < 8; ++ks) qf[ks] = *(const f16x8*)(Qrow + ks * 32);

  f32x4 acc[16] = {};
  float run_m = -1e30f, run_l = 0.f;
  const float sm_scale = 0.03125f;  // 1/sqrt(1024)
  const int ntiles = q0 / 32 + 1;

  for (int kt = 0; kt < ntiles; ++kt) {
    // --- QK^T partial over this wave's 256 features ---
    f32x4 s0 = {0.f, 0.f, 0.f, 0.f}, s1 = {0.f, 0.f, 0.f, 0.f};
    const _Float16* Kbase =
        Kb + (size_t)(b * T_SEQ + kt * 32 + lr) * ADIM + fbase + g * 8;
#pragma unroll
    for (int ks = 0; ks < 8; ++ks) {
      f16x8 k0f = *(const f16x8*)(Kbase + ks * 32);
      f16x8 k1f = *(const f16x8*)(Kbase + (size_t)16 * ADIM + ks * 32);
      s0 = __builtin_amdgcn_mfma_f32_16x16x32_f16(qf[ks], k0f, s0, 0, 0, 0);
      s1 = __builtin_amdgcn_mfma_f32_16x16x32_f16(qf[ks], k1f, s1, 0, 0, 0);
    }
    // write partials: rows 4g+r, cols jn*16+lr
    {
      float* Sp = &S_lds[w * 512];
#pragma unroll
      for (int r = 0; r < 4; r++) {
        Sp[(4 * g + r) * 32 + lr] = s0[r];
        Sp[(4 * g + r) * 32 + 16 + lr] = s1[r];
      }
    }
    __syncthreads();
    // --- reduce 4 feature-partials ---
#pragma unroll
    for (int e = tid; e < 1024; e += 512) {
      const int wqi = e >> 9, rem = e & 511;
      S_red[e] = S_lds[(wqi * 4 + 0) * 512 + rem] + S_lds[(wqi * 4 + 1) * 512 + rem] +
                 S_lds[(wqi * 4 + 2) * 512 + rem] + S_lds[(wqi * 4 + 3) * 512 + rem];
    }
    __syncthreads();
    // --- softmax (lane owns row lr, cols 8g+j) ---
    float p[8];
    float tmax = -1e30f;
    const int kb = kt * 32;
#pragma unroll
    for (int j = 0; j < 8; j++) {
      float sv = S_red[wq * 512 + lr * 32 + 8 * g + j] * sm_scale;
      const int tkey = kb + 8 * g + j;
      sv = (tkey > qrow) ? -1e30f : sv;
      p[j] = sv;
      tmax = fmaxf(tmax, sv);
    }
    tmax = fmaxf(tmax, __shfl_xor(tmax, 16));
    tmax = fmaxf(tmax, __shfl_xor(tmax, 32));
    const float newm = fmaxf(run_m, tmax);
    const float scale = __expf(run_m - newm);
    float rowsum = 0.f;
#pragma unroll
    for (int j = 0; j < 8; j++) {
      const float pe = __expf(p[j] - newm);
      p[j] = pe;
      rowsum += pe;
    }
    rowsum += __shfl_xor(rowsum, 16);
    rowsum += __shfl_xor(rowsum, 32);
    run_l = run_l * scale + rowsum;
    run_m = newm;
    // rescale accumulator (acc rows are 4g+r; fetch per-row scale via shfl)
    float sc[4];
#pragma unroll
    for (int r = 0; r < 4; r++) sc[r] = __shfl(scale, 4 * g + r);
#pragma unroll
    for (int jf = 0; jf < 16; jf++)
#pragma unroll
      for (int r = 0; r < 4; r++) acc[jf][r] *= sc[r];
    // P fragment: lane already holds exactly row lr, tokens 8g+j
    f16x8 pf;
#pragma unroll
    for (int j = 0; j < 8; j++) pf[j] = (_Float16)p[j];
    // --- PV: B-frag from Vt (feature rows, token-contiguous) ---
    const _Float16* Vbase =
        Vt + ((size_t)b * ADIM + fbase + lr) * T_SEQ + kb + g * 8;
#pragma unroll
    for (int jf = 0; jf < 16; ++jf) {
      f16x8 vf = *(const f16x8*)(Vbase + (size_t)jf * 16 * T_SEQ);
      acc[jf] = __builtin_amdgcn_mfma_f32_16x16x32_f16(pf, vf, acc[jf], 0, 0, 0);
    }
  }

  // --- epilogue: divide by running sum, write f32 ---
  float invl[4];
#pragma unroll
  for (int r = 0; r < 4; r++) invl[r] = 1.f / __shfl(run_l, 4 * g + r);
#pragma unroll
  for (int jf = 0; jf < 16; jf++)
#pragma unroll
    for (int r = 0; r < 4; r++) {
      const int row = q0 + wq * 16 + 4 * g + r;
      const int col = fbase + jf * 16 + lr;
      Out[((size_t)b * T_SEQ + row) * ADIM + col] = acc[jf][r] * invl[r];
    }
}

// ---------------- launch ----------------
extern "C" void kernel_launch(void* const* d_in, const int* in_sizes, int n_in,
                              void* d_out, int out_size, void* d_ws, size_t ws_size,
                              hipStream_t stream) {
  const float* X = (const float*)d_in[0];
  const float* Wk = (const float*)d_in[1];
  const float* Wq = (const float*)d_in[2];
  const float* Wv = (const float*)d_in[3];
  float* Out = (float*)d_out;

  char* ws = (char*)d_ws;
  const size_t WT_BYTES = (size_t)3 * EDIM * ADIM * 2;          // 6 MB
  const size_t MAT_BYTES = (size_t)MTOT * ADIM * 2;             // 32 MB
  _Float16* Wt = (_Float16*)ws;
  _Float16* Kb = (_Float16*)(ws + WT_BYTES);
  _Float16* Qb = (_Float16*)(ws + WT_BYTES + MAT_BYTES);
  _Float16* Vt = (_Float16*)(ws + WT_BYTES + 2 * MAT_BYTES);

  cast_transpose_w<<<dim3(32, 32, 3), dim3(32, 8), 0, stream>>>(Wk, Wq, Wv, Wt);
  gemm_qkv<<<dim3(ADIM / 128, MTOT / 128, 3), dim3(256), 0, stream>>>(X, Wt, Qb, Kb, Vt);
  flash_attn<<<dim3(T_SEQ / 32, NBATCH), dim3(512), 0, stream>>>(Qb, Kb, Vt, Out);
}

// Round 2
// 696.371 us; speedup vs baseline: 3.3951x; 3.3951x over previous
//
#include <hip/hip_runtime.h>
#include <hip/hip_fp16.h>

#define T_SEQ 4096
#define NBATCH 4
#define EDIM 1024
#define ADIM 1024
#define MTOT (NBATCH * T_SEQ)  // 16384

typedef _Float16 f16x8 __attribute__((ext_vector_type(8)));
typedef float f32x4 __attribute__((ext_vector_type(4)));

// ---------------- Kernel 1: cast + transpose weights to f16 ----------------
__global__ __launch_bounds__(256) void cast_transpose_w(
    const float* __restrict__ Wk, const float* __restrict__ Wq,
    const float* __restrict__ Wv, _Float16* __restrict__ Wt) {
  __shared__ float tile[32][33];
  const int z = blockIdx.z;
  const float* W = (z == 0) ? Wk : (z == 1) ? Wq : Wv;
  const int n0 = blockIdx.x * 32, k0 = blockIdx.y * 32;
  const int tx = threadIdx.x, ty = threadIdx.y;  // block (32,8)
#pragma unroll
  for (int yy = 0; yy < 32; yy += 8)
    tile[ty + yy][tx] = W[(size_t)(k0 + ty + yy) * ADIM + n0 + tx];
  __syncthreads();
  _Float16* out = Wt + (size_t)z * EDIM * ADIM;
#pragma unroll
  for (int yy = 0; yy < 32; yy += 8)
    out[(size_t)(n0 + ty + yy) * EDIM + k0 + tx] = (_Float16)tile[tx][ty + yy];
}

// ---------------- Kernel 2: QKV projection GEMM ----------------
__global__ __launch_bounds__(256) void gemm_qkv(
    const float* __restrict__ X, const _Float16* __restrict__ Wt,
    _Float16* __restrict__ Qb, _Float16* __restrict__ Kb,
    _Float16* __restrict__ Vt) {
  const int z = blockIdx.z;
  const _Float16* Bt = Wt + (size_t)z * EDIM * ADIM;
  __shared__ __align__(16) _Float16 Al[128 * 32];
  __shared__ __align__(16) _Float16 Bl[128 * 32];
  const int tid = threadIdx.x;
  const int lane = tid & 63, w = tid >> 6;
  const int wm = w >> 1, wn = w & 1;
  const int lr = lane & 15, g = lane >> 4;
  const int m0 = blockIdx.y * 128, n0 = blockIdx.x * 128;
  const int arow = tid >> 1;
  const int ahalf = tid & 1;

  f32x4 acc[4][4] = {};

  for (int k0 = 0; k0 < EDIM; k0 += 32) {
    {
      const float* src = X + (size_t)(m0 + arow) * EDIM + k0 + ahalf * 16;
      float4 v0 = ((const float4*)src)[0];
      float4 v1 = ((const float4*)src)[1];
      float4 v2 = ((const float4*)src)[2];
      float4 v3 = ((const float4*)src)[3];
      f16x8 pa = {(_Float16)v0.x, (_Float16)v0.y, (_Float16)v0.z, (_Float16)v0.w,
                  (_Float16)v1.x, (_Float16)v1.y, (_Float16)v1.z, (_Float16)v1.w};
      f16x8 pb = {(_Float16)v2.x, (_Float16)v2.y, (_Float16)v2.z, (_Float16)v2.w,
                  (_Float16)v3.x, (_Float16)v3.y, (_Float16)v3.z, (_Float16)v3.w};
      *(f16x8*)&Al[arow * 32 + ahalf * 16] = pa;
      *(f16x8*)&Al[arow * 32 + ahalf * 16 + 8] = pb;
    }
#pragma unroll
    for (int t = 0; t < 2; ++t) {
      const int r0 = (w * 2 + t) * 16;
      const _Float16* gsrc =
          Bt + (size_t)(n0 + r0 + (lane >> 2)) * EDIM + k0 + (lane & 3) * 8;
      __builtin_amdgcn_global_load_lds(
          (const __attribute__((address_space(1))) void*)gsrc,
          (__attribute__((address_space(3))) void*)&Bl[r0 * 32], 16, 0, 0);
    }
    __syncthreads();
    f16x8 af[4], bf[4];
#pragma unroll
    for (int i = 0; i < 4; i++)
      af[i] = *(const f16x8*)&Al[(wm * 64 + i * 16 + lr) * 32 + g * 8];
#pragma unroll
    for (int j = 0; j < 4; j++)
      bf[j] = *(const f16x8*)&Bl[(wn * 64 + j * 16 + lr) * 32 + g * 8];
#pragma unroll
    for (int i = 0; i < 4; i++)
#pragma unroll
      for (int j = 0; j < 4; j++)
        acc[i][j] = __builtin_amdgcn_mfma_f32_16x16x32_f16(af[i], bf[j], acc[i][j], 0, 0, 0);
    __syncthreads();
  }

#pragma unroll
  for (int i = 0; i < 4; i++)
#pragma unroll
    for (int j = 0; j < 4; j++)
#pragma unroll
      for (int r = 0; r < 4; r++) {
        const int row = m0 + wm * 64 + i * 16 + 4 * g + r;
        const int col = n0 + wn * 64 + j * 16 + lr;
        const _Float16 hv = (_Float16)acc[i][j][r];
        if (z == 0)
          Kb[(size_t)row * ADIM + col] = hv;
        else if (z == 1)
          Qb[(size_t)row * ADIM + col] = hv;
        else {
          const int b = row >> 12, tt = row & 4095;
          Vt[((size_t)b * ADIM + col) * T_SEQ + tt] = hv;
        }
      }
}

// ---------------- Kernel 3: S = Q K^T (causal lower-tri blocks) ----------------
// S[b][i][j] = sum_f Q[b][i][f] * K[b][j][f]   (raw, unscaled; f16 out)
__global__ __launch_bounds__(256) void gemm_sqk(
    const _Float16* __restrict__ Qb, const _Float16* __restrict__ Kb,
    _Float16* __restrict__ Sb) {
  const int bj = blockIdx.x, bi = blockIdx.y, b = blockIdx.z;
  if (bj > bi) return;  // fully-masked block
  __shared__ __align__(16) _Float16 Al[128 * 32];
  __shared__ __align__(16) _Float16 Bl[128 * 32];
  const int tid = threadIdx.x;
  const int lane = tid & 63, w = tid >> 6;
  const int wm = w >> 1, wn = w & 1;
  const int lr = lane & 15, g = lane >> 4;
  const int m0 = bi * 128, n0 = bj * 128;
  const _Float16* A = Qb + (size_t)b * T_SEQ * ADIM;
  const _Float16* B = Kb + (size_t)b * T_SEQ * ADIM;

  f32x4 acc[4][4] = {};

  for (int k0 = 0; k0 < ADIM; k0 += 32) {
#pragma unroll
    for (int t = 0; t < 2; ++t) {
      const int r0 = (w * 2 + t) * 16;
      const _Float16* ga =
          A + (size_t)(m0 + r0 + (lane >> 2)) * ADIM + k0 + (lane & 3) * 8;
      __builtin_amdgcn_global_load_lds(
          (const __attribute__((address_space(1))) void*)ga,
          (__attribute__((address_space(3))) void*)&Al[r0 * 32], 16, 0, 0);
      const _Float16* gb =
          B + (size_t)(n0 + r0 + (lane >> 2)) * ADIM + k0 + (lane & 3) * 8;
      __builtin_amdgcn_global_load_lds(
          (const __attribute__((address_space(1))) void*)gb,
          (__attribute__((address_space(3))) void*)&Bl[r0 * 32], 16, 0, 0);
    }
    __syncthreads();
    f16x8 af[4], bf[4];
#pragma unroll
    for (int i = 0; i < 4; i++)
      af[i] = *(const f16x8*)&Al[(wm * 64 + i * 16 + lr) * 32 + g * 8];
#pragma unroll
    for (int j = 0; j < 4; j++)
      bf[j] = *(const f16x8*)&Bl[(wn * 64 + j * 16 + lr) * 32 + g * 8];
#pragma unroll
    for (int i = 0; i < 4; i++)
#pragma unroll
      for (int j = 0; j < 4; j++)
        acc[i][j] = __builtin_amdgcn_mfma_f32_16x16x32_f16(af[i], bf[j], acc[i][j], 0, 0, 0);
    __syncthreads();
  }

  _Float16* Srow = Sb + (size_t)b * T_SEQ * T_SEQ;
#pragma unroll
  for (int i = 0; i < 4; i++)
#pragma unroll
    for (int j = 0; j < 4; j++)
#pragma unroll
      for (int r = 0; r < 4; r++) {
        const int row = m0 + wm * 64 + i * 16 + 4 * g + r;
        const int col = n0 + wn * 64 + j * 16 + lr;
        Srow[(size_t)row * T_SEQ + col] = (_Float16)acc[i][j][r];
      }
}

// ---------------- Kernel 4: row softmax (in place, causal mask) ----------------
__global__ __launch_bounds__(512) void softmax_rows(_Float16* __restrict__ S) {
  const int i = blockIdx.x, b = blockIdx.y;
  const int padded = ((i >> 7) + 1) << 7;  // valid block region for this row
  const int tid = threadIdx.x;
  const int lane = tid & 63, w = tid >> 6;
  const int j0 = tid * 8;
  const bool active = j0 < padded;
  _Float16* row = S + ((size_t)b * T_SEQ + i) * T_SEQ;
  const float sm_scale = 0.03125f;  // 1/sqrt(1024)

  float v[8];
  float m = -1e30f;
  if (active) {
    f16x8 x = *(const f16x8*)(row + j0);
#pragma unroll
    for (int jj = 0; jj < 8; jj++) {
      const float sv = (j0 + jj <= i) ? (float)x[jj] * sm_scale : -1e30f;
      v[jj] = sv;
      m = fmaxf(m, sv);
    }
  } else {
#pragma unroll
    for (int jj = 0; jj < 8; jj++) v[jj] = -1e30f;
  }
#pragma unroll
  for (int off = 1; off < 64; off <<= 1) m = fmaxf(m, __shfl_xor(m, off));
  __shared__ float redm[8], reds[8];
  if (lane == 0) redm[w] = m;
  __syncthreads();
#pragma unroll
  for (int ww = 0; ww < 8; ww++) m = fmaxf(m, redm[ww]);

  float s = 0.f;
#pragma unroll
  for (int jj = 0; jj < 8; jj++) {
    v[jj] = __expf(v[jj] - m);
    s += v[jj];
  }
#pragma unroll
  for (int off = 1; off < 64; off <<= 1) s += __shfl_xor(s, off);
  if (lane == 0) reds[w] = s;
  __syncthreads();
  s = 0.f;
#pragma unroll
  for (int ww = 0; ww < 8; ww++) s += reds[ww];
  const float inv = 1.f / s;

  if (active) {
    f16x8 o;
#pragma unroll
    for (int jj = 0; jj < 8; jj++) o[jj] = (_Float16)(v[jj] * inv);
    *(f16x8*)(row + j0) = o;
  }
}

// ---------------- Kernel 5: O = P V (causal: variable K extent) ----------------
// O[b][i][f] = sum_j P[b][i][j] * Vt[b][f][j]
__global__ __launch_bounds__(256) void gemm_pv(
    const _Float16* __restrict__ Pb, const _Float16* __restrict__ Vt,
    float* __restrict__ Out) {
  const int bx = blockIdx.x, by = blockIdx.y, b = blockIdx.z;
  __shared__ __align__(16) _Float16 Al[128 * 32];
  __shared__ __align__(16) _Float16 Bl[128 * 32];
  const int tid = threadIdx.x;
  const int lane = tid & 63, w = tid >> 6;
  const int wm = w >> 1, wn = w & 1;
  const int lr = lane & 15, g = lane >> 4;
  const int m0 = by * 128, n0 = bx * 128;
  const int kmax = (by + 1) * 128;
  const _Float16* A = Pb + (size_t)b * T_SEQ * T_SEQ;   // lda = T_SEQ
  const _Float16* B = Vt + (size_t)b * ADIM * T_SEQ;    // ldb = T_SEQ

  f32x4 acc[4][4] = {};

  for (int k0 = 0; k0 < kmax; k0 += 32) {
#pragma unroll
    for (int t = 0; t < 2; ++t) {
      const int r0 = (w * 2 + t) * 16;
      const _Float16* ga =
          A + (size_t)(m0 + r0 + (lane >> 2)) * T_SEQ + k0 + (lane & 3) * 8;
      __builtin_amdgcn_global_load_lds(
          (const __attribute__((address_space(1))) void*)ga,
          (__attribute__((address_space(3))) void*)&Al[r0 * 32], 16, 0, 0);
      const _Float16* gb =
          B + (size_t)(n0 + r0 + (lane >> 2)) * T_SEQ + k0 + (lane & 3) * 8;
      __builtin_amdgcn_global_load_lds(
          (const __attribute__((address_space(1))) void*)gb,
          (__attribute__((address_space(3))) void*)&Bl[r0 * 32], 16, 0, 0);
    }
    __syncthreads();
    f16x8 af[4], bf[4];
#pragma unroll
    for (int i = 0; i < 4; i++)
      af[i] = *(const f16x8*)&Al[(wm * 64 + i * 16 + lr) * 32 + g * 8];
#pragma unroll
    for (int j = 0; j < 4; j++)
      bf[j] = *(const f16x8*)&Bl[(wn * 64 + j * 16 + lr) * 32 + g * 8];
#pragma unroll
    for (int i = 0; i < 4; i++)
#pragma unroll
      for (int j = 0; j < 4; j++)
        acc[i][j] = __builtin_amdgcn_mfma_f32_16x16x32_f16(af[i], bf[j], acc[i][j], 0, 0, 0);
    __syncthreads();
  }

#pragma unroll
  for (int i = 0; i < 4; i++)
#pragma unroll
    for (int j = 0; j < 4; j++)
#pragma unroll
      for (int r = 0; r < 4; r++) {
        const int row = m0 + wm * 64 + i * 16 + 4 * g + r;
        const int col = n0 + wn * 64 + j * 16 + lr;
        Out[((size_t)b * T_SEQ + row) * ADIM + col] = acc[i][j][r];
      }
}

// ---------------- launch ----------------
extern "C" void kernel_launch(void* const* d_in, const int* in_sizes, int n_in,
                              void* d_out, int out_size, void* d_ws, size_t ws_size,
                              hipStream_t stream) {
  const float* X = (const float*)d_in[0];
  const float* Wk = (const float*)d_in[1];
  const float* Wq = (const float*)d_in[2];
  const float* Wv = (const float*)d_in[3];
  float* Out = (float*)d_out;

  char* ws = (char*)d_ws;
  const size_t WT_BYTES = (size_t)3 * EDIM * ADIM * 2;   // 6 MB
  const size_t MAT_BYTES = (size_t)MTOT * ADIM * 2;      // 32 MB each
  _Float16* Wt = (_Float16*)ws;
  _Float16* Kb = (_Float16*)(ws + WT_BYTES);
  _Float16* Qb = (_Float16*)(ws + WT_BYTES + MAT_BYTES);
  _Float16* Vt = (_Float16*)(ws + WT_BYTES + 2 * MAT_BYTES);
  _Float16* Sb = (_Float16*)(ws + WT_BYTES + 3 * MAT_BYTES);  // 128 MB

  cast_transpose_w<<<dim3(32, 32, 3), dim3(32, 8), 0, stream>>>(Wk, Wq, Wv, Wt);
  gemm_qkv<<<dim3(ADIM / 128, MTOT / 128, 3), dim3(256), 0, stream>>>(X, Wt, Qb, Kb, Vt);
  gemm_sqk<<<dim3(32, 32, NBATCH), dim3(256), 0, stream>>>(Qb, Kb, Sb);
  softmax_rows<<<dim3(T_SEQ, NBATCH), dim3(512), 0, stream>>>(Sb);
  gemm_pv<<<dim3(ADIM / 128, T_SEQ / 128, NBATCH), dim3(256), 0, stream>>>(Sb, Vt, Out);
}